// Round 8
// baseline (1203.883 us; speedup 1.0000x reference)
//
#include <hip/hip_runtime.h>
#include <cmath>

#define MSG 128
#define TILE 32      // edges per LDS tile (16 KB staged)
#define TPB 256      // 4 waves; each wave owns 32 hidden units
#define NB_MAX 768   // 3 blocks/CU -> 3 independent pipeline streams

typedef __attribute__((ext_vector_type(8))) __bf16 bf16x8;
typedef __attribute__((ext_vector_type(4))) float f32x4;

__device__ __forceinline__ unsigned short f2bf(float f) {
  union { float f; unsigned u; } v; v.f = f;
  unsigned r = v.u + 0x7FFFu + ((v.u >> 16) & 1u);  // round-to-nearest-even
  return (unsigned short)(r >> 16);
}

// ---- Kernel 1: convert + transpose both hidden-layer weight matrices to bf16.
__global__ void prep_weights_kernel(const float* __restrict__ Ww1,
                                    const float* __restrict__ Wa1,
                                    unsigned short* __restrict__ WtW,
                                    unsigned short* __restrict__ WtA) {
  int idx = blockIdx.x * blockDim.x + threadIdx.x;
  if (idx < MSG * MSG) {
    int k = idx >> 7;
    int n = idx & 127;
    WtW[n * MSG + k] = f2bf(Ww1[idx]);
    WtA[n * MSG + k] = f2bf(Wa1[idx]);
  }
}

__device__ __forceinline__ void gload_lds16(const float* g, float* l) {
  __builtin_amdgcn_global_load_lds(
      (const __attribute__((address_space(1))) void*)g,
      (__attribute__((address_space(3))) void*)l, 16, 0, 0);
}

// ---- Kernel 2: persistent pipelined edge pass, 3 streams/CU, 4-wave blocks.
// Wave-uniform vmcnt queue discipline (hand-verified; all waves identical):
//   loop-top outstanding: [at(t-1)=4, x(t)=6]
//   +sd(t+1)=2, +stg(t+1)=4            -> 16
//   barrier A;  vmcnt(6)   : drains at,x      (leaves sd2+stg4)
//   finalize(t) +at(t)=4               -> 10
//   vmcnt(8)   : drains sd(t+1)               (leaves stg4+at4)
//   +x(t+1)=6                          -> 14
//   vmcnt(10)  : drains stg(t+1)              (leaves at4+x6)  barrier B
// Staging is NEVER drained by a dependent use; finalize data for tile t was
// prefetched during t-1 (registers). All loads unconditional via clamped
// indices; invalid atomic addends are 0.0f (harmless adds).
__global__ __launch_bounds__(TPB, 3)
void edge_mlp_pipe_kernel(const float* __restrict__ m_ij,
                          const unsigned short* __restrict__ WtW,
                          const unsigned short* __restrict__ WtA,
                          const float* __restrict__ bw1, const float* __restrict__ Ww2,
                          const float* __restrict__ bw2,
                          const float* __restrict__ ba1, const float* __restrict__ Wa2,
                          const float* __restrict__ ba2,
                          const int* __restrict__ src,
                          const int* __restrict__ dst,
                          const float* __restrict__ x,
                          float* __restrict__ num4, int E, int ntiles) {
  __shared__ __align__(16) float buf[2][TILE * MSG];  // 2 x 16KB, swizzled rows
  __shared__ float plds[2][4][TILE];                  // [mlp][wave][edge] 1KB

  const int tid = threadIdx.x;
  const int w = tid >> 6;       // 0..3
  const int lane = tid & 63;
  const int quad = lane >> 4;
  const int l16 = lane & 15;

  // --- Persistent weights: wave w owns hidden units [32w, 32w+32).
  bf16x8 wf[2][2][4];            // [nt][mat W/A][kt]
  f32x4 c1[2][2], c2[2][2];      // [nt][mat]: layer-1 bias, layer-2 weight
  #pragma unroll
  for (int nt = 0; nt < 2; ++nt) {
    const int unit16 = w * 32 + nt * 16;
    const size_t ro = (size_t)(unit16 + l16) * MSG + quad * 8;
    #pragma unroll
    for (int kt = 0; kt < 4; ++kt) {
      wf[nt][0][kt] = *(const bf16x8*)(WtW + ro + kt * 32);
      wf[nt][1][kt] = *(const bf16x8*)(WtA + ro + kt * 32);
    }
    const int co = unit16 + quad * 4;
    c1[nt][0] = *(const f32x4*)(bw1 + co);
    c2[nt][0] = *(const f32x4*)(Ww2 + co);
    c1[nt][1] = *(const f32x4*)(ba1 + co);
    c2[nt][1] = *(const f32x4*)(Wa2 + co);
  }
  const float bw2s = bw2[0], ba2s = ba2[0];

  // Stage one 32x128 fp32 tile (16KB). LDS dest linear; XOR swizzle
  // (byte ^= (row&7)<<4) applied to the GLOBAL source (T21).
  auto stage = [&](int tile, int bsel) {
    #pragma unroll
    for (int i = 0; i < 4; ++i) {
      const int chunk = i * TPB + tid;        // 0..1023
      const int db = chunk * 16;              // [0, 16384)
      const int row = db >> 9;                // 512B rows
      const int col = db & 511;
      const int scol = col ^ ((row & 7) << 4);
      int grow = tile * TILE + row;
      if (grow >= E) grow = E - 1;
      gload_lds16(m_ij + (size_t)grow * MSG + (scol >> 2), &buf[bsel][0] + (db >> 2));
    }
  };

  // Finalize mapping: lane owns edge fid of each tile (8 per wave, x8 lane
  // redundancy on loads -- same cache line; atomics by quad==0 && l16<8).
  const int fid = w * 8 + (lane & 7);

  // ---- Prologue: prefetch tile t0's finalize data + stage t0.
  int tt = blockIdx.x;
  int ge = tt * TILE + fid;
  bool vcur = (ge < E);
  int gec = vcur ? ge : 0;
  int sN = src[gec];
  int dN = dst[gec];
  asm volatile("" ::: "memory");            // pin sd issue above staging
  stage(tt, 0);
  asm volatile("s_waitcnt vmcnt(4)" ::: "memory");   // sd ready (stg in flight)
  float sx = x[3 * sN], sy = x[3 * sN + 1], sz = x[3 * sN + 2];
  float gx = x[3 * dN], gy = x[3 * dN + 1], gz = x[3 * dN + 2];
  asm volatile("s_waitcnt vmcnt(6)" ::: "memory");   // stg(t0) done (x6 fly)
  __builtin_amdgcn_s_barrier();
  int cur = 0;

  for (; tt < ntiles; tt += gridDim.x) {
    const int nxt = tt + (int)gridDim.x;
    const int snxt = (nxt < ntiles) ? nxt : (ntiles - 1);

    // (A) sd(t+1) issue-only (oldest after the invariant queue).
    const int geN = snxt * TILE + fid;
    const bool vnxt = (geN < E);
    const int geNc = vnxt ? geN : 0;
    const int sN2 = src[geNc];
    const int dN2 = dst[geNc];
    asm volatile("" ::: "memory");          // pin above staging
    // (B) fire-and-forget staging of tile t+1.
    stage(snxt, cur ^ 1);

    // (C) Compute tile t: 2 edge sub-tiles of 16 from swizzled LDS.
    #pragma unroll
    for (int et = 0; et < 2; ++et) {
      const int row = et * 16 + l16;
      const int rbase = row * MSG;
      const int xorf = (row & 7) << 2;      // float-index xor (= byte<<4)
      bf16x8 bfv[4];
      #pragma unroll
      for (int kt = 0; kt < 4; ++kt) {
        const int c0 = quad * 8 + kt * 32;
        const f32x4 v0 = *(const f32x4*)(&buf[cur][rbase + (c0 ^ xorf)]);
        const f32x4 v1 = *(const f32x4*)(&buf[cur][rbase + ((c0 + 4) ^ xorf)]);
        bf16x8 f;
        f[0] = (__bf16)v0.x; f[1] = (__bf16)v0.y;
        f[2] = (__bf16)v0.z; f[3] = (__bf16)v0.w;
        f[4] = (__bf16)v1.x; f[5] = (__bf16)v1.y;
        f[6] = (__bf16)v1.z; f[7] = (__bf16)v1.w;
        bfv[kt] = f;
      }
      f32x4 acc[2][2];
      #pragma unroll
      for (int nt = 0; nt < 2; ++nt) {
        acc[nt][0] = {0.f, 0.f, 0.f, 0.f};
        acc[nt][1] = {0.f, 0.f, 0.f, 0.f};
      }
      #pragma unroll
      for (int kt = 0; kt < 4; ++kt) {
        #pragma unroll
        for (int nt = 0; nt < 2; ++nt) {
          acc[nt][0] = __builtin_amdgcn_mfma_f32_16x16x32_bf16(wf[nt][0][kt], bfv[kt], acc[nt][0], 0, 0, 0);
          acc[nt][1] = __builtin_amdgcn_mfma_f32_16x16x32_bf16(wf[nt][1][kt], bfv[kt], acc[nt][1], 0, 0, 0);
        }
      }
      float pW = 0.f, pA = 0.f;
      #pragma unroll
      for (int nt = 0; nt < 2; ++nt) {
        #pragma unroll
        for (int r = 0; r < 4; ++r) {
          const float hw = acc[nt][0][r] + c1[nt][0][r];
          const float ha = acc[nt][1][r] + c1[nt][1][r];
          // silu via rcp: saturation-safe.
          pW += (hw * c2[nt][0][r]) * __builtin_amdgcn_rcpf(1.f + __expf(-hw));
          pA += (ha * c2[nt][1][r]) * __builtin_amdgcn_rcpf(1.f + __expf(-ha));
        }
      }
      pW += __shfl_xor(pW, 16, 64); pW += __shfl_xor(pW, 32, 64);
      pA += __shfl_xor(pA, 16, 64); pA += __shfl_xor(pA, 32, 64);
      if (quad == 0) {
        plds[0][w][et * 16 + l16] = pW;
        plds[1][w][et * 16 + l16] = pA;
      }
    }

    // Barrier A: partials visible.
    asm volatile("s_waitcnt lgkmcnt(0)" ::: "memory");
    __builtin_amdgcn_s_barrier();

    // (D) x(t)/at(t-1) drained; sd(t+1)+stg(t+1) stay in flight.
    asm volatile("s_waitcnt vmcnt(6)" ::: "memory");

    // (E) Finalize tile t with prefetched registers; atomics always issued
    // (8 lanes/wave active, never execz), invalid addends are 0.0f.
    {
      float sW = 0.f, sA = 0.f;
      #pragma unroll
      for (int ww = 0; ww < 4; ++ww) {
        sW += plds[0][ww][fid];
        sA += plds[1][ww][fid];
      }
      const float a = __expf(sA + ba2s);
      const float t = (sW + bw2s) * a;
      const float dx = gx - sx, dy = gy - sy, dz = gz - sz;
      const float nrm = sqrtf(dx * dx + dy * dy + dz * dz);
      const float inv = t * __builtin_amdgcn_rcpf(fmaxf(nrm, 1e-12f));
      const float m = vcur ? 1.f : 0.f;
      if (quad == 0 && l16 < 8) {
        float* basep = num4 + (size_t)4 * sN;
        atomicAdd(basep + 0, dx * inv * m);
        atomicAdd(basep + 1, dy * inv * m);
        atomicAdd(basep + 2, dz * inv * m);
        atomicAdd(basep + 3, a * m);
      }
    }

    // (F) sd(t+1) readable (stg4+at4 stay); issue x(t+1).
    asm volatile("s_waitcnt vmcnt(8)" ::: "memory");
    const float sx2 = x[3 * sN2], sy2 = x[3 * sN2 + 1], sz2 = x[3 * sN2 + 2];
    const float gx2 = x[3 * dN2], gy2 = x[3 * dN2 + 1], gz2 = x[3 * dN2 + 2];

    // (G) Barrier B: stg(t+1) landed; at4+x6 remain in flight.
    asm volatile("s_waitcnt vmcnt(10) lgkmcnt(0)" ::: "memory");
    __builtin_amdgcn_s_barrier();

    // Rotate prefetch registers.
    sN = sN2; dN = dN2; vcur = vnxt;
    sx = sx2; sy = sy2; sz = sz2;
    gx = gx2; gy = gy2; gz = gz2;
    cur ^= 1;
  }
}

// ---- Kernel 3: per-node finalize. out = x + num.xyz / num.w (0 if no edges).
__global__ void finalize_kernel(const float* __restrict__ x,
                                const f32x4* __restrict__ num4,
                                float* __restrict__ out, int N) {
  int n = blockIdx.x * blockDim.x + threadIdx.x;
  if (n >= N) return;
  const f32x4 v = num4[n];
  const float inv = (v[3] != 0.f) ? __builtin_amdgcn_rcpf(v[3]) : 0.f;
  out[3 * n + 0] = x[3 * n + 0] + v[0] * inv;
  out[3 * n + 1] = x[3 * n + 1] + v[1] * inv;
  out[3 * n + 2] = x[3 * n + 2] + v[2] * inv;
}

extern "C" void kernel_launch(void* const* d_in, const int* in_sizes, int n_in,
                              void* d_out, int out_size, void* d_ws, size_t ws_size,
                              hipStream_t stream) {
  const float* x    = (const float*)d_in[0];
  const float* m_ij = (const float*)d_in[1];
  const int*   edges = (const int*)d_in[2];
  const float* Ww1 = (const float*)d_in[3];
  const float* bw1 = (const float*)d_in[4];
  const float* Ww2 = (const float*)d_in[5];
  const float* bw2 = (const float*)d_in[6];
  const float* Wa1 = (const float*)d_in[7];
  const float* ba1 = (const float*)d_in[8];
  const float* Wa2 = (const float*)d_in[9];
  const float* ba2 = (const float*)d_in[10];

  const int N = in_sizes[0] / 3;
  const int E = in_sizes[1] / MSG;
  const int* src = edges;        // edges[0] = receiver
  const int* dst = edges + E;    // edges[1] = neighbor

  // Workspace layout (~1.7 MB)
  char* p = (char*)d_ws;
  unsigned short* WtW = (unsigned short*)p; p += (size_t)MSG * MSG * 2;
  unsigned short* WtA = (unsigned short*)p; p += (size_t)MSG * MSG * 2;
  float* num4 = (float*)p; p += (size_t)N * 4 * 4;

  float* out = (float*)d_out;

  const int ntiles = (E + TILE - 1) / TILE;
  const int nb = ntiles < NB_MAX ? ntiles : NB_MAX;

  hipMemsetAsync(num4, 0, (size_t)N * 4 * 4, stream);
  prep_weights_kernel<<<(MSG * MSG + 255) / 256, 256, 0, stream>>>(Ww1, Wa1, WtW, WtA);
  edge_mlp_pipe_kernel<<<nb, TPB, 0, stream>>>(
      m_ij, WtW, WtA, bw1, Ww2, bw2, ba1, Wa2, ba2, src, dst, x, num4, E, ntiles);
  finalize_kernel<<<(N + 255) / 256, 256, 0, stream>>>(x, (const f32x4*)num4, out, N);
}